// Round 1
// baseline (106.107 us; speedup 1.0000x reference)
//
#include <hip/hip_runtime.h>
#include <hip/hip_bf16.h>
#include <math.h>

// Problem constants from the reference: B=64, H=192, W=192, STRIDE=8, EPS=1e-7
#define STRIDE_F 8.0f
#define EPS_F 1e-7f
#define PI_2_F 1.57079632679489662f

// Fast reciprocal: v_rcp_f32, ~1 ulp — far inside the 1.56e-2 tolerance.
__device__ __forceinline__ float frcp(float x) { return __builtin_amdgcn_rcpf(x); }

// atan(w / (h)) for w >= 0, h > 0, branch-free.
// Range-reduce via min/max so the poly argument z = min/max is in [0,1];
// degree-11 odd minimax poly, max err ~1e-5 rad.
__device__ __forceinline__ float fast_atan_ratio(float w, float h)
{
    float num = fminf(w, h);
    float den = fmaxf(w, h);
    float z   = num * frcp(den);
    float z2  = z * z;
    float p = fmaf(z2, -0.0117212f,  0.05265332f);
    p = fmaf(z2, p, -0.11643287f);
    p = fmaf(z2, p,  0.19354346f);
    p = fmaf(z2, p, -0.33262347f);
    p = fmaf(z2, p,  0.99997726f);
    p = z * p;
    return (w > h) ? (PI_2_F - p) : p;
}

__device__ __forceinline__ void ciou_elem(
    float cx, float cy,
    float pl, float pt, float pr, float pb,
    float tl, float tt, float tr, float tb,
    int m_i, float& ls, float& ms)
{
    float px1 = cx - pl * STRIDE_F;
    float py1 = cy - pt * STRIDE_F;
    float px2 = cx + pr * STRIDE_F;
    float py2 = cy + pb * STRIDE_F;
    float tx1 = cx - tl * STRIDE_F;
    float ty1 = cy - tt * STRIDE_F;
    float tx2 = cx + tr * STRIDE_F;
    float ty2 = cy + tb * STRIDE_F;

    float w1 = px2 - px1, h1 = py2 - py1;
    float w2 = tx2 - tx1, h2 = ty2 - ty1;
    float iw = fmaxf(fminf(px2, tx2) - fmaxf(px1, tx1), 0.0f);
    float ih = fmaxf(fminf(py2, ty2) - fmaxf(py1, ty1), 0.0f);
    float inter = iw * ih;
    float uni   = w1 * h1 + w2 * h2 - inter + EPS_F;
    float iou   = inter * frcp(uni);

    float cw = fmaxf(px2, tx2) - fminf(px1, tx1);
    float ch = fmaxf(py2, ty2) - fminf(py1, ty1);
    float c2 = cw * cw + ch * ch + EPS_F;

    float dx = tx1 + tx2 - px1 - px2;
    float dy = ty1 + ty2 - py1 - py2;
    float rho2 = (dx * dx + dy * dy) * 0.25f;

    const float FOUR_OVER_PI2 = 0.40528473456935109f; // 4/pi^2
    // w,h >= 0 here (inputs are non-negative offsets), h2+EPS > 0.
    float dv = fast_atan_ratio(w2, h2 + EPS_F) - fast_atan_ratio(w1, h1 + EPS_F);
    float v  = FOUR_OVER_PI2 * dv * dv;
    float alpha = v * frcp(v - iou + (1.0f + EPS_F));
    float ciou  = iou - rho2 * frcp(c2) - alpha * v;

    float m = (m_i != 0) ? 1.0f : 0.0f;
    ls += (1.0f - ciou) * m;
    ms += m;
}

// Process one float4-group of 4 elements given preloaded data.
__device__ __forceinline__ void ciou_group(
    float cx0, float cy,
    const float4& pl4, const float4& pt4, const float4& pr4, const float4& pb4,
    const float4& tl4, const float4& tt4, const float4& tr4, const float4& tb4,
    const int4& mk4, float& ls, float& ms)
{
    ciou_elem(cx0 + 0.0f * STRIDE_F, cy, pl4.x, pt4.x, pr4.x, pb4.x,
              tl4.x, tt4.x, tr4.x, tb4.x, mk4.x, ls, ms);
    ciou_elem(cx0 + 1.0f * STRIDE_F, cy, pl4.y, pt4.y, pr4.y, pb4.y,
              tl4.y, tt4.y, tr4.y, tb4.y, mk4.y, ls, ms);
    ciou_elem(cx0 + 2.0f * STRIDE_F, cy, pl4.z, pt4.z, pr4.z, pb4.z,
              tl4.z, tt4.z, tr4.z, tb4.z, mk4.z, ls, ms);
    ciou_elem(cx0 + 3.0f * STRIDE_F, cy, pl4.w, pt4.w, pr4.w, pb4.w,
              tl4.w, tt4.w, tr4.w, tb4.w, mk4.w, ls, ms);
}

// Each thread handles TWO float4-groups: tid and tid+half4 (far split keeps
// every load instruction fully coalesced: lane i touches group base+i).
// 18 x 16B loads are issued before any compute -> deep MLP per wave.
__global__ __launch_bounds__(256) void ciou_loss_kernel(
    const float4* __restrict__ pred, const float4* __restrict__ tgt,
    const int4* __restrict__ mask, float2* __restrict__ parts,
    int HW4, int W4, int half4)
{
    int tid = blockIdx.x * blockDim.x + threadIdx.x;
    int idx4a = tid;
    int idx4b = tid + half4;

    // index math for both groups
    int bba = idx4a / HW4;
    int hw4a = idx4a - bba * HW4;
    int ha = hw4a / W4;
    int w4a = hw4a - ha * W4;

    int bbb = idx4b / HW4;
    int hw4b = idx4b - bbb * HW4;
    int hb = hw4b / W4;
    int w4b = hw4b - hb * W4;

    size_t basea = (size_t)bba * 4 * (size_t)HW4 + (size_t)hw4a;
    size_t baseb = (size_t)bbb * 4 * (size_t)HW4 + (size_t)hw4b;

    // ---- issue all 18 loads up front ----
    float4 pla = pred[basea];
    float4 pta = pred[basea + (size_t)HW4];
    float4 pra = pred[basea + 2 * (size_t)HW4];
    float4 pba = pred[basea + 3 * (size_t)HW4];
    float4 tla = tgt[basea];
    float4 tta = tgt[basea + (size_t)HW4];
    float4 tra = tgt[basea + 2 * (size_t)HW4];
    float4 tba = tgt[basea + 3 * (size_t)HW4];
    int4   mka = mask[idx4a];

    float4 plb = pred[baseb];
    float4 ptb = pred[baseb + (size_t)HW4];
    float4 prb = pred[baseb + 2 * (size_t)HW4];
    float4 pbb = pred[baseb + 3 * (size_t)HW4];
    float4 tlb = tgt[baseb];
    float4 ttb = tgt[baseb + (size_t)HW4];
    float4 trb = tgt[baseb + 2 * (size_t)HW4];
    float4 tbb = tgt[baseb + 3 * (size_t)HW4];
    int4   mkb = mask[idx4b];

    float cya = ((float)ha + 0.5f) * STRIDE_F;
    float cx0a = ((float)(w4a * 4) + 0.5f) * STRIDE_F;
    float cyb = ((float)hb + 0.5f) * STRIDE_F;
    float cx0b = ((float)(w4b * 4) + 0.5f) * STRIDE_F;

    float ls = 0.0f, ms = 0.0f;
    ciou_group(cx0a, cya, pla, pta, pra, pba, tla, tta, tra, tba, mka, ls, ms);
    ciou_group(cx0b, cyb, plb, ptb, prb, pbb, tlb, ttb, trb, tbb, mkb, ls, ms);

    // wave-64 reduction
    #pragma unroll
    for (int off = 32; off > 0; off >>= 1) {
        ls += __shfl_down(ls, off, 64);
        ms += __shfl_down(ms, off, 64);
    }
    __shared__ float s_l[4];
    __shared__ float s_m[4];
    int wave = threadIdx.x >> 6;
    int lane = threadIdx.x & 63;
    if (lane == 0) { s_l[wave] = ls; s_m[wave] = ms; }
    __syncthreads();
    if (threadIdx.x == 0) {
        float2 p;
        p.x = s_l[0] + s_l[1] + s_l[2] + s_l[3];
        p.y = s_m[0] + s_m[1] + s_m[2] + s_m[3];
        parts[blockIdx.x] = p;
    }
}

__global__ __launch_bounds__(256) void reduce_kernel(
    const float2* __restrict__ parts, int n, float* __restrict__ out)
{
    float ls = 0.0f, ms = 0.0f;
    for (int i = threadIdx.x; i < n; i += 256) {
        float2 p = parts[i];
        ls += p.x;
        ms += p.y;
    }
    #pragma unroll
    for (int off = 32; off > 0; off >>= 1) {
        ls += __shfl_down(ls, off, 64);
        ms += __shfl_down(ms, off, 64);
    }
    __shared__ float s_l[4];
    __shared__ float s_m[4];
    int wave = threadIdx.x >> 6;
    int lane = threadIdx.x & 63;
    if (lane == 0) { s_l[wave] = ls; s_m[wave] = ms; }
    __syncthreads();
    if (threadIdx.x == 0) {
        float tls = s_l[0] + s_l[1] + s_l[2] + s_l[3];
        float tms = s_m[0] + s_m[1] + s_m[2] + s_m[3];
        out[0] = tls / fmaxf(tms, 1.0f);
    }
}

extern "C" void kernel_launch(void* const* d_in, const int* in_sizes, int n_in,
                              void* d_out, int out_size, void* d_ws, size_t ws_size,
                              hipStream_t stream) {
    const float4* pred = (const float4*)d_in[0];
    const float4* tgt  = (const float4*)d_in[1];
    const int4*   mask = (const int4*)d_in[2];
    float* out  = (float*)d_out;
    float2* parts = (float2*)d_ws;

    const int B = 64, H = 192, W = 192;
    const int HW = H * W;
    const int total4 = B * HW / 4;        // 589824
    const int half4  = total4 / 2;        // 294912
    const int threads = 256;
    const int blocks = half4 / threads;   // 1152, exact

    ciou_loss_kernel<<<blocks, threads, 0, stream>>>(pred, tgt, mask, parts,
                                                     HW / 4, W / 4, half4);
    reduce_kernel<<<1, threads, 0, stream>>>(parts, blocks, out);
}

// Round 2
// 106.091 us; speedup vs baseline: 1.0002x; 1.0002x over previous
//
#include <hip/hip_runtime.h>
#include <math.h>

// Problem constants: B=64, H=192, W=192, STRIDE=8, EPS=1e-7.
// All geometry is computed in STRIDE units: the grid-cell center (cx,cy)
// cancels out of every CIoU term, and the stride factor 8 cancels in all
// ratios (epsilons rescaled: union/c2 eps /64, atan-denominator eps /8).
#define EPS_F 1e-7f
#define PI_2_F 1.57079632679489662f

constexpr int kHW4    = (192 * 192) / 4;  // 9216 float4-groups per (b,channel) plane
constexpr int kTotal4 = 64 * kHW4;        // 589824
constexpr int kHalf4  = kTotal4 / 2;      // 294912
constexpr int kThreads = 256;
constexpr int kBlocks  = kHalf4 / kThreads; // 1152, exact

// Fast reciprocal: v_rcp_f32, ~1 ulp — far inside the 1.56e-2 tolerance.
__device__ __forceinline__ float frcp(float x) { return __builtin_amdgcn_rcpf(x); }

// atan(w / h) for w >= 0, h > 0, branch-free.
// Range-reduce via min/max so z = min/max is in [0,1]; degree-11 odd
// minimax poly, max err ~1e-5 rad.
__device__ __forceinline__ float fast_atan_ratio(float w, float h)
{
    float num = fminf(w, h);
    float den = fmaxf(w, h);
    float z   = num * frcp(den);
    float z2  = z * z;
    float p = fmaf(z2, -0.0117212f,  0.05265332f);
    p = fmaf(z2, p, -0.11643287f);
    p = fmaf(z2, p,  0.19354346f);
    p = fmaf(z2, p, -0.33262347f);
    p = fmaf(z2, p,  0.99997726f);
    p = z * p;
    return (w > h) ? (PI_2_F - p) : p;
}

// CIoU contribution of one element, all in stride units.
// pl,pt,pr,pb / tl,tt,tr,tb are the raw (non-negative) l,t,r,b offsets.
__device__ __forceinline__ void ciou_elem(
    float pl, float pt, float pr, float pb,
    float tl, float tt, float tr, float tb,
    int m_i, float& ls, float& ms)
{
    const float EPS_U = EPS_F * (1.0f / 64.0f); // eps / stride^2
    const float EPS_H = EPS_F * 0.125f;         // eps / stride
    const float FOUR_OVER_PI2 = 0.40528473456935109f;
    const float ONEP = 1.0f + EPS_F;

    float mnl = fminf(pl, tl), mnr = fminf(pr, tr);
    float mnt = fminf(pt, tt), mnb = fminf(pb, tb);
    float mxl = fmaxf(pl, tl), mxr = fmaxf(pr, tr);
    float mxt = fmaxf(pt, tt), mxb = fmaxf(pb, tb);

    float w1 = pl + pr, h1 = pt + pb;      // pred w,h
    float w2 = tl + tr, h2 = tt + tb;      // target w,h
    float iw = mnl + mnr, ih = mnt + mnb;  // intersection (>=0: inputs >= 0)
    float cw = mxl + mxr, ch = mxt + mxb;  // enclosing box

    float inter = iw * ih;
    float uni   = fmaf(w1, h1, fmaf(w2, h2, EPS_U - inter));
    float iou   = inter * frcp(uni);

    float dx = (pl - pr) + (tr - tl);      // center delta * 2 (sign-free: squared)
    float dy = (pt - pb) + (tb - tt);
    float d2 = fmaf(dx, dx, dy * dy);
    float cc = fmaf(cw, cw, fmaf(ch, ch, EPS_U));
    float rr = (0.25f * d2) * frcp(cc);    // rho2 / c2

    float dv = fast_atan_ratio(w2, h2 + EPS_H) - fast_atan_ratio(w1, h1 + EPS_H);
    float v  = (FOUR_OVER_PI2 * dv) * dv;
    float av = (v * v) * frcp((v - iou) + ONEP); // alpha * v

    float ciou = (iou - rr) - av;
    bool mm = (m_i != 0);
    ls += mm ? (1.0f - ciou) : 0.0f;
    ms += mm ? 1.0f : 0.0f;
}

__device__ __forceinline__ void ciou_group(
    const float4& pl4, const float4& pt4, const float4& pr4, const float4& pb4,
    const float4& tl4, const float4& tt4, const float4& tr4, const float4& tb4,
    const int4& mk4, float& ls, float& ms)
{
    ciou_elem(pl4.x, pt4.x, pr4.x, pb4.x, tl4.x, tt4.x, tr4.x, tb4.x, mk4.x, ls, ms);
    ciou_elem(pl4.y, pt4.y, pr4.y, pb4.y, tl4.y, tt4.y, tr4.y, tb4.y, mk4.y, ls, ms);
    ciou_elem(pl4.z, pt4.z, pr4.z, pb4.z, tl4.z, tt4.z, tr4.z, tb4.z, mk4.z, ls, ms);
    ciou_elem(pl4.w, pt4.w, pr4.w, pb4.w, tl4.w, tt4.w, tr4.w, tb4.w, mk4.w, ls, ms);
}

// Each thread handles TWO float4-groups: tid and tid+kHalf4 (far split keeps
// every load instruction fully coalesced). 18 x 16B loads issued before any
// compute. No per-element position math: (cx,cy) cancels out of CIoU.
__global__ __launch_bounds__(256) void ciou_loss_kernel(
    const float4* __restrict__ pred, const float4* __restrict__ tgt,
    const int4* __restrict__ mask, float2* __restrict__ parts)
{
    int tid  = blockIdx.x * kThreads + threadIdx.x;
    int ia   = tid;
    int ib   = tid + kHalf4;

    // b-index via compile-time magic-multiply division
    int ba = ia / kHW4;
    int pa = ia - ba * kHW4;
    int bb = ib / kHW4;
    int pb = ib - bb * kHW4;

    size_t basea = (size_t)ba * (4 * kHW4) + (size_t)pa;
    size_t baseb = (size_t)bb * (4 * kHW4) + (size_t)pb;

    // ---- issue all 18 loads up front ----
    float4 pla = pred[basea];
    float4 pta = pred[basea + kHW4];
    float4 pra = pred[basea + 2 * kHW4];
    float4 pba = pred[basea + 3 * kHW4];
    float4 tla = tgt[basea];
    float4 tta = tgt[basea + kHW4];
    float4 tra = tgt[basea + 2 * kHW4];
    float4 tba = tgt[basea + 3 * kHW4];
    int4   mka = mask[ia];

    float4 plb = pred[baseb];
    float4 ptb = pred[baseb + kHW4];
    float4 prb = pred[baseb + 2 * kHW4];
    float4 pbb = pred[baseb + 3 * kHW4];
    float4 tlb = tgt[baseb];
    float4 ttb = tgt[baseb + kHW4];
    float4 trb = tgt[baseb + 2 * kHW4];
    float4 tbb = tgt[baseb + 3 * kHW4];
    int4   mkb = mask[ib];

    float ls = 0.0f, ms = 0.0f;
    ciou_group(pla, pta, pra, pba, tla, tta, tra, tba, mka, ls, ms);
    ciou_group(plb, ptb, prb, pbb, tlb, ttb, trb, tbb, mkb, ls, ms);

    // wave-64 reduction
    #pragma unroll
    for (int off = 32; off > 0; off >>= 1) {
        ls += __shfl_down(ls, off, 64);
        ms += __shfl_down(ms, off, 64);
    }
    __shared__ float s_l[4];
    __shared__ float s_m[4];
    int wave = threadIdx.x >> 6;
    int lane = threadIdx.x & 63;
    if (lane == 0) { s_l[wave] = ls; s_m[wave] = ms; }
    __syncthreads();
    if (threadIdx.x == 0) {
        float2 p;
        p.x = s_l[0] + s_l[1] + s_l[2] + s_l[3];
        p.y = s_m[0] + s_m[1] + s_m[2] + s_m[3];
        parts[blockIdx.x] = p;
    }
}

__global__ __launch_bounds__(256) void reduce_kernel(
    const float2* __restrict__ parts, float* __restrict__ out)
{
    float ls = 0.0f, ms = 0.0f;
    for (int i = threadIdx.x; i < kBlocks; i += kThreads) {
        float2 p = parts[i];
        ls += p.x;
        ms += p.y;
    }
    #pragma unroll
    for (int off = 32; off > 0; off >>= 1) {
        ls += __shfl_down(ls, off, 64);
        ms += __shfl_down(ms, off, 64);
    }
    __shared__ float s_l[4];
    __shared__ float s_m[4];
    int wave = threadIdx.x >> 6;
    int lane = threadIdx.x & 63;
    if (lane == 0) { s_l[wave] = ls; s_m[wave] = ms; }
    __syncthreads();
    if (threadIdx.x == 0) {
        float tls = s_l[0] + s_l[1] + s_l[2] + s_l[3];
        float tms = s_m[0] + s_m[1] + s_m[2] + s_m[3];
        out[0] = tls / fmaxf(tms, 1.0f);
    }
}

extern "C" void kernel_launch(void* const* d_in, const int* in_sizes, int n_in,
                              void* d_out, int out_size, void* d_ws, size_t ws_size,
                              hipStream_t stream) {
    const float4* pred = (const float4*)d_in[0];
    const float4* tgt  = (const float4*)d_in[1];
    const int4*   mask = (const int4*)d_in[2];
    float* out  = (float*)d_out;
    float2* parts = (float2*)d_ws;

    ciou_loss_kernel<<<kBlocks, kThreads, 0, stream>>>(pred, tgt, mask, parts);
    reduce_kernel<<<1, kThreads, 0, stream>>>(parts, out);
}